// Round 8
// baseline (1535.523 us; speedup 1.0000x reference)
//
#include <hip/hip_runtime.h>
#include <hip/hip_bf16.h>
#include <math.h>

#define NHEAD 4
#define HC 256

typedef short short8 __attribute__((ext_vector_type(8)));
typedef short short4v __attribute__((ext_vector_type(4)));
typedef float f32x4 __attribute__((ext_vector_type(4)));

__device__ inline f32x4 bf4_to_f32(short4v v)
{
  f32x4 r;
#pragma unroll
  for (int i = 0; i < 4; ++i)
    r[i] = __uint_as_float(((unsigned)(unsigned short)v[i]) << 16);
  return r;
}

// ------- one fused prep kernel: all fp32->bf16 conversions, all weight
// transposes/concats, and the degree count (grid-partitioned ranges) -------
__global__ void prep_kernel(
    const float* __restrict__ x, const float* __restrict__ fp,
    const float* __restrict__ c1Wl, const float* __restrict__ c1Wr,
    const float* __restrict__ c2Wl, const float* __restrict__ c2Wr,
    const float* __restrict__ fW, const float* __restrict__ gW,
    const float* __restrict__ k1W, const int* __restrict__ dst,
    int* __restrict__ deg,
    __hip_bfloat16* __restrict__ xbf, __hip_bfloat16* __restrict__ fpbf,
    __hip_bfloat16* __restrict__ wt1, __hip_bfloat16* __restrict__ wt2,
    __hip_bfloat16* __restrict__ fwt, __hip_bfloat16* __restrict__ gwt,
    __hip_bfloat16* __restrict__ k1wt, int N, int G, int E)
{
  const int n0 = N * 32, n1 = G * 2048, n2 = 512 * 32, n3 = 512 * 256;
  const int n4 = 256 * 2048, n5 = 64 * 256, n6 = 192 * 384;
  int idx = blockIdx.x * 256 + threadIdx.x;
  if (idx < n0) { xbf[idx] = __float2bfloat16(x[idx]); return; }
  idx -= n0;
  if (idx < n1) { fpbf[idx] = __float2bfloat16(fp[idx]); return; }
  idx -= n1;
  if (idx < n2) {
    int n = idx / 32, k = idx - n * 32;
    float v = (n < 256) ? c1Wl[k * 256 + n] : c1Wr[k * 256 + (n - 256)];
    wt1[idx] = __float2bfloat16(v); return;
  }
  idx -= n2;
  if (idx < n3) {
    int n = idx / 256, k = idx - n * 256;
    float v = (n < 256) ? c2Wl[k * 256 + n] : c2Wr[k * 256 + (n - 256)];
    wt2[idx] = __float2bfloat16(v); return;
  }
  idx -= n3;
  if (idx < n4) {
    int n = idx / 2048, k = idx - n * 2048;
    fwt[idx] = __float2bfloat16(fW[(long)k * 256 + n]); return;
  }
  idx -= n4;
  if (idx < n5) {
    int n = idx / 256, k = idx - n * 256;
    gwt[idx] = __float2bfloat16(gW[k * 64 + n]); return;
  }
  idx -= n5;
  if (idx < n6) {
    int n = idx / 384, k = idx - n * 384;
    k1wt[idx] = __float2bfloat16(k1W[k * 192 + n]); return;
  }
  idx -= n6;
  if (idx < E) atomicAdd(&deg[dst[idx]], 1);
}

// ------- bf16 MFMA GEMM: [xl|xr] = A[M][K] @ W[K][512] + bias -> bf16 tables -
__global__ __launch_bounds__(256) void gemm_mfma_kernel(
    const __hip_bfloat16* __restrict__ A, const __hip_bfloat16* __restrict__ BT,
    const float* __restrict__ bl, const float* __restrict__ br,
    __hip_bfloat16* __restrict__ XL, __hip_bfloat16* __restrict__ XR, int M, int K)
{
  __shared__ short As[128 * 40];
  __shared__ short Bs[64 * 40];
  int bm = blockIdx.x * 128, bn = blockIdx.y * 64;
  int t = threadIdx.x;
  int w = t >> 6, l = t & 63;
  int quad = l >> 4, l16 = l & 15;
  int col8 = (t & 3) * 8;

  f32x4 acc[2][4];
#pragma unroll
  for (int i = 0; i < 2; ++i)
#pragma unroll
    for (int j = 0; j < 4; ++j) acc[i][j] = (f32x4){0.f, 0.f, 0.f, 0.f};

  for (int k0 = 0; k0 < K; k0 += 32) {
#pragma unroll
    for (int p = 0; p < 2; ++p) {
      int row = (t >> 2) + p * 64;
      *(short8*)&As[row * 40 + col8] =
          *(const short8*)(const void*)&A[(long)(bm + row) * K + k0 + col8];
    }
    {
      int n = t >> 2;
      *(short8*)&Bs[n * 40 + col8] =
          *(const short8*)(const void*)&BT[(long)(bn + n) * K + k0 + col8];
    }
    __syncthreads();
    short8 af[2], bf[4];
#pragma unroll
    for (int mt = 0; mt < 2; ++mt)
      af[mt] = *(short8*)&As[(w * 32 + mt * 16 + l16) * 40 + quad * 8];
#pragma unroll
    for (int nt = 0; nt < 4; ++nt)
      bf[nt] = *(short8*)&Bs[(nt * 16 + l16) * 40 + quad * 8];
#pragma unroll
    for (int mt = 0; mt < 2; ++mt)
#pragma unroll
      for (int nt = 0; nt < 4; ++nt)
        acc[mt][nt] = __builtin_amdgcn_mfma_f32_16x16x32_bf16(af[mt], bf[nt], acc[mt][nt], 0, 0, 0);
    __syncthreads();
  }
#pragma unroll
  for (int mt = 0; mt < 2; ++mt)
#pragma unroll
    for (int nt = 0; nt < 4; ++nt) {
      int col = bn + nt * 16 + l16;
      float b = (col < 256) ? bl[col] : br[col - 256];
#pragma unroll
      for (int r = 0; r < 4; ++r) {
        int row = bm + w * 32 + mt * 16 + quad * 4 + r;
        float v = acc[mt][nt][r] + b;
        if (col < 256)
          XL[(long)row * 256 + col] = __float2bfloat16(v);
        else
          XR[(long)row * 256 + (col - 256)] = __float2bfloat16(v);
      }
    }
}

// ------- bf16 MFMA GEMM + relu + bn epilogue; out bf16 (obf=1) or fp32 -------
// A[M][K] bf16, BT[N][K] bf16 n-major. Tile 64x64, grid (M/64, N/64).
__global__ __launch_bounds__(256) void gemm_rb_kernel(
    const __hip_bfloat16* __restrict__ A, const __hip_bfloat16* __restrict__ BT,
    const float* __restrict__ bias, const float* __restrict__ gamma,
    const float* __restrict__ beta, void* __restrict__ out,
    int M, int K, int ldc, int coloff, int obf)
{
  __shared__ short As[64 * 40];
  __shared__ short Bs[64 * 40];
  int bm = blockIdx.x * 64, bn = blockIdx.y * 64;
  int t = threadIdx.x;
  int w = t >> 6, l = t & 63;
  int quad = l >> 4, l16 = l & 15;
  int lrow = t >> 2, col8 = (t & 3) * 8;

  f32x4 acc[4];
#pragma unroll
  for (int nt = 0; nt < 4; ++nt) acc[nt] = (f32x4){0.f, 0.f, 0.f, 0.f};

  for (int k0 = 0; k0 < K; k0 += 32) {
    *(short8*)&As[lrow * 40 + col8] =
        *(const short8*)(const void*)&A[(long)(bm + lrow) * K + k0 + col8];
    *(short8*)&Bs[lrow * 40 + col8] =
        *(const short8*)(const void*)&BT[(long)(bn + lrow) * K + k0 + col8];
    __syncthreads();
    short8 af = *(short8*)&As[(w * 16 + l16) * 40 + quad * 8];
#pragma unroll
    for (int nt = 0; nt < 4; ++nt) {
      short8 bf = *(short8*)&Bs[(nt * 16 + l16) * 40 + quad * 8];
      acc[nt] = __builtin_amdgcn_mfma_f32_16x16x32_bf16(af, bf, acc[nt], 0, 0, 0);
    }
    __syncthreads();
  }
  const float inv = rsqrtf(1.f + 1e-5f);
#pragma unroll
  for (int nt = 0; nt < 4; ++nt) {
    int col = bn + nt * 16 + l16;
    float b = bias[col], gm = gamma[col] * inv, bt = beta[col];
#pragma unroll
    for (int r = 0; r < 4; ++r) {
      int row = bm + w * 16 + quad * 4 + r;
      float v = fmaxf(acc[nt][r] + b, 0.f) * gm + bt;
      if (obf)
        ((__hip_bfloat16*)out)[(long)row * ldc + coloff + col] = __float2bfloat16(v);
      else
        ((float*)out)[(long)row * ldc + coloff + col] = v;
    }
  }
}

// -------- scalar dense layer (desc branch): out = bn(relu(A@W+b)) -> bf16 ---
__global__ __launch_bounds__(256) void dense_kernel(
    const float* __restrict__ A, const float* __restrict__ W,
    const float* __restrict__ bias, const float* __restrict__ gamma,
    const float* __restrict__ beta, __hip_bfloat16* __restrict__ out,
    int M, int Ncols, int K, int ldc, int coloff)
{
  int idx = blockIdx.x * 256 + threadIdx.x;
  if (idx >= M * Ncols) return;
  int row = idx / Ncols, col = idx - row * Ncols;
  const float* a = A + (long)row * K;
  float acc = 0.f;
#pragma unroll 4
  for (int k = 0; k < K; ++k) acc = fmaf(a[k], W[(long)k * Ncols + col], acc);
  const float inv = rsqrtf(1.f + 1e-5f);
  acc = fmaxf(acc + bias[col], 0.f) * (gamma[col] * inv) + beta[col];
  out[(long)row * ldc + coloff + col] = __float2bfloat16(acc);
}

// -------- fused k2+k3 head --------
__global__ __launch_bounds__(256) void head23_kernel(
    const float* __restrict__ z1, const float* __restrict__ k2W,
    const float* __restrict__ k2b, const float* __restrict__ k2_gn,
    const float* __restrict__ k2_bt, const float* __restrict__ k3W,
    const float* __restrict__ k3b, float* __restrict__ out)
{
  __shared__ float s1[16 * 192];
  __shared__ float s2[16 * 96];
  int b = blockIdx.x, t = threadIdx.x;
  for (int i = t; i < 16 * 192; i += 256) s1[i] = z1[(long)b * 16 * 192 + i];
  __syncthreads();
  const float inv = rsqrtf(1.f + 1e-5f);
#pragma unroll
  for (int j = 0; j < 6; ++j) {
    int idx = j * 256 + t;
    int row = idx / 96, col = idx - row * 96;
    float acc = 0.f;
#pragma unroll 4
    for (int k = 0; k < 192; ++k) acc = fmaf(s1[row * 192 + k], k2W[k * 96 + col], acc);
    acc = fmaxf(acc + k2b[col], 0.f);
    s2[idx] = acc * (k2_gn[col] * inv) + k2_bt[col];
  }
  __syncthreads();
  if (t < 192) {
    int row = t / 12, col = t - row * 12;
    float acc = 0.f;
#pragma unroll 4
    for (int k = 0; k < 96; ++k) acc = fmaf(s2[row * 96 + k], k3W[k * 12 + col], acc);
    out[(long)(b * 16 + row) * 12 + col] = acc + k3b[col];
  }
}

// ---------------- CSR build ----------------
__global__ __launch_bounds__(1024) void scan_kernel(
    const int* __restrict__ deg, int* __restrict__ ptr, int* __restrict__ cursor, int N)
{
  __shared__ int sums[1024];
  int t = threadIdx.x;
  int base = t * 32;
  int local[32];
  int s = 0;
#pragma unroll
  for (int i = 0; i < 32; ++i) {
    int v = (base + i < N) ? deg[base + i] : 0;
    local[i] = v; s += v;
  }
  sums[t] = s;
  __syncthreads();
  for (int off = 1; off < 1024; off <<= 1) {
    int v = (t >= off) ? sums[t - off] : 0;
    __syncthreads();
    sums[t] += v;
    __syncthreads();
  }
  int excl = sums[t] - s;
  for (int i = 0; i < 32; ++i) {
    if (base + i < N) { ptr[base + i] = excl; cursor[base + i] = excl; excl += local[i]; }
  }
  if (t == 1023) ptr[N] = sums[1023];
}

// scatter src id AND edge_attr into CSR order
__global__ void fill_kernel(const int* __restrict__ src, const int* __restrict__ dst,
                            const float* __restrict__ ea, int* __restrict__ cursor,
                            int* __restrict__ csr_src, float* __restrict__ csr_ea, int E)
{
  int e = blockIdx.x * blockDim.x + threadIdx.x;
  if (e < E) {
    int pos = atomicAdd(&cursor[dst[e]], 1);
    csr_src[pos] = src[e];
    f32x4 a0 = *(const f32x4*)(const void*)&ea[(long)e * 8];
    f32x4 a1 = *(const f32x4*)(const void*)&ea[(long)e * 8 + 4];
    *(f32x4*)&csr_ea[(long)pos * 8] = a0;
    *(f32x4*)&csr_ea[(long)pos * 8 + 4] = a1;
  }
}

// ---------------- GATv2 aggregation ----------------
// lane = head*16 + quad; lane owns 4 channels of one head; 2 nodes / 128-thr
// block, pinned at 8 waves/EU (VGPR<=64). Softmax without max-subtraction
// (shift-invariant; 0.05-scale weights bound |logit|). 2-deep NAMED prefetch.
__global__ __launch_bounds__(128, 8) void gat_kernel(
    const __hip_bfloat16* __restrict__ xlb, const __hip_bfloat16* __restrict__ xrb,
    const float* __restrict__ csr_ea, const int* __restrict__ csr_src,
    const int* __restrict__ csr_ptr,
    const float* __restrict__ We, const float* __restrict__ att,
    const float* __restrict__ bias, __hip_bfloat16* __restrict__ out, int N)
{
  int lane = threadIdx.x & 63;
  int node = blockIdx.x * 2 + (threadIdx.x >> 6);
  if (node >= N) return;
  int cbase = (lane >> 4) * 64 + (lane & 15) * 4;  // channel offset in [0,256)

  f32x4 attv = *(const f32x4*)(const void*)&att[cbase];
  f32x4 xriv = bf4_to_f32(*(const short4v*)(const void*)&xrb[(long)node * HC + cbase]);
  f32x4 biasv = *(const f32x4*)(const void*)&bias[cbase];
  f32x4 WeR[8];
#pragma unroll
  for (int d = 0; d < 8; ++d)
    WeR[d] = *(const f32x4*)(const void*)&We[d * HC + cbase];

  float rsum = 0.f;
  f32x4 acc = (f32x4){0.f, 0.f, 0.f, 0.f};
  f32x4 eas0 = (f32x4){0.f, 0.f, 0.f, 0.f};
  f32x4 eas1 = (f32x4){0.f, 0.f, 0.f, 0.f};

  int p0 = csr_ptr[node], p1 = csr_ptr[node + 1];

  auto edge_compute = [&](f32x4 xls, f32x4 ea0, f32x4 ea1) {
    f32x4 mv = xriv + xls;
#pragma unroll
    for (int d = 0; d < 4; ++d) mv += WeR[d] * ea0[d];
#pragma unroll
    for (int d = 0; d < 4; ++d) mv += WeR[d + 4] * ea1[d];
    float t = 0.f;
#pragma unroll
    for (int r = 0; r < 4; ++r) {
      float m = mv[r];
      m = (m > 0.f) ? m : 0.2f * m;
      t = fmaf(m, attv[r], t);
    }
    t += __shfl_xor(t, 1, 64);
    t += __shfl_xor(t, 2, 64);
    t += __shfl_xor(t, 4, 64);
    t += __shfl_xor(t, 8, 64);
    float p = __expf(t);
    rsum += p;
    acc += p * xls;
  };

  // 2-deep prefetch, named slots A/B (runtime-indexed arrays kill codegen)
  short4v xA = (short4v){0, 0, 0, 0}, xB = (short4v){0, 0, 0, 0};
  f32x4 a0A = (f32x4){0.f, 0.f, 0.f, 0.f}, a1A = a0A, a0B = a0A, a1B = a0A;
  if (p0 < p1) {
    int s = csr_src[p0];
    a0A = *(const f32x4*)(const void*)&csr_ea[(long)p0 * 8];
    a1A = *(const f32x4*)(const void*)&csr_ea[(long)p0 * 8 + 4];
    xA = *(const short4v*)(const void*)&xlb[(long)s * HC + cbase];
  }
  if (p0 + 1 < p1) {
    int s = csr_src[p0 + 1];
    a0B = *(const f32x4*)(const void*)&csr_ea[(long)(p0 + 1) * 8];
    a1B = *(const f32x4*)(const void*)&csr_ea[(long)(p0 + 1) * 8 + 4];
    xB = *(const short4v*)(const void*)&xlb[(long)s * HC + cbase];
  }
  int k = p0;
  for (; k + 2 <= p1; k += 2) {
    f32x4 e0 = a0A, e1 = a1A;
    short4v xc = xA;
    if (k + 2 < p1) {
      int s = csr_src[k + 2];
      a0A = *(const f32x4*)(const void*)&csr_ea[(long)(k + 2) * 8];
      a1A = *(const f32x4*)(const void*)&csr_ea[(long)(k + 2) * 8 + 4];
      xA = *(const short4v*)(const void*)&xlb[(long)s * HC + cbase];
    }
    eas0 += e0; eas1 += e1;
    edge_compute(bf4_to_f32(xc), e0, e1);

    e0 = a0B; e1 = a1B; xc = xB;
    if (k + 3 < p1) {
      int s = csr_src[k + 3];
      a0B = *(const f32x4*)(const void*)&csr_ea[(long)(k + 3) * 8];
      a1B = *(const f32x4*)(const void*)&csr_ea[(long)(k + 3) * 8 + 4];
      xB = *(const short4v*)(const void*)&xlb[(long)s * HC + cbase];
    }
    eas0 += e0; eas1 += e1;
    edge_compute(bf4_to_f32(xc), e0, e1);
  }
  if (k < p1) {           // odd tail lives in slot A
    eas0 += a0A; eas1 += a1A;
    edge_compute(bf4_to_f32(xA), a0A, a1A);
  }
  // self loop with mean edge_attr
  int cnt = p1 - p0;
  f32x4 xls_self = bf4_to_f32(*(const short4v*)(const void*)&xlb[(long)node * HC + cbase]);
  float invd = 1.f / (float)(cnt > 1 ? cnt : 1);
  edge_compute(xls_self, eas0 * invd, eas1 * invd);

  float invs = 1.f / rsum;
  short4v pk;
#pragma unroll
  for (int r = 0; r < 4; ++r) {
    float v = fmaxf(acc[r] * invs + biasv[r], 0.f);
    __hip_bfloat16 hv = __float2bfloat16(v);
    pk[r] = *(short*)&hv;
  }
  *(short4v*)&out[(long)node * HC + cbase] = pk;
}

// ---------------- segmented global max pool (bf16 in, bf16 out) ------------
__global__ __launch_bounds__(256) void pool_seg_kernel(
    const __hip_bfloat16* __restrict__ h, __hip_bfloat16* __restrict__ xg, int npg)
{
  int g = blockIdx.x, c = threadIdx.x;
  const __hip_bfloat16* base = h + (long)g * npg * HC + c;
  float m = -INFINITY;
#pragma unroll 4
  for (int i = 0; i < npg; ++i) {
    unsigned short u = *(const unsigned short*)&base[(long)i * HC];
    m = fmaxf(m, __uint_as_float(((unsigned)u) << 16));
  }
  xg[(long)g * HC + c] = __float2bfloat16(m);   // exact: max of bf16 values
}

extern "C" void kernel_launch(void* const* d_in, const int* in_sizes, int n_in,
                              void* d_out, int out_size, void* d_ws, size_t ws_size,
                              hipStream_t stream)
{
  const float* x          = (const float*)d_in[0];
  const int*   edge_index = (const int*)d_in[1];
  const float* edge_attr  = (const float*)d_in[2];
  const float* fp         = (const float*)d_in[4];
  const float* desc       = (const float*)d_in[5];
  const float *c1_Wl = (const float*)d_in[6],  *c1_bl = (const float*)d_in[7],
              *c1_Wr = (const float*)d_in[8],  *c1_br = (const float*)d_in[9],
              *c1_We = (const float*)d_in[10], *c1_att = (const float*)d_in[11],
              *c1_bias = (const float*)d_in[12];
  const float *c2_Wl = (const float*)d_in[13], *c2_bl = (const float*)d_in[14],
              *c2_Wr = (const float*)d_in[15], *c2_br = (const float*)d_in[16],
              *c2_We = (const float*)d_in[17], *c2_att = (const float*)d_in[18],
              *c2_bias = (const float*)d_in[19];
  const float *gW = (const float*)d_in[20], *gb = (const float*)d_in[21],
              *g_gn = (const float*)d_in[22], *g_bt = (const float*)d_in[23];
  const float *fW = (const float*)d_in[24], *fb = (const float*)d_in[25],
              *f_gn = (const float*)d_in[26], *f_bt = (const float*)d_in[27];
  const float *dW = (const float*)d_in[28], *db = (const float*)d_in[29],
              *d_gn = (const float*)d_in[30], *d_bt = (const float*)d_in[31];
  const float *k1W = (const float*)d_in[32], *k1b = (const float*)d_in[33],
              *k1_gn = (const float*)d_in[34], *k1_bt = (const float*)d_in[35];
  const float *k2W = (const float*)d_in[36], *k2b = (const float*)d_in[37],
              *k2_gn = (const float*)d_in[38], *k2_bt = (const float*)d_in[39];
  const float *k3W = (const float*)d_in[40], *k3b = (const float*)d_in[41];

  const int N = in_sizes[0] / 32;       // 32768
  const int E = in_sizes[1] / 2;        // 262144
  const int G = in_sizes[4] / 2048;     // 1024
  const int FIN = 32, FPIN = 2048;
  const int DIN = in_sizes[5] / G;      // 200

  char* ws = (char*)d_ws;
  size_t off = 0;
  auto alloc = [&](size_t bytes) {
    void* p = ws + off;
    off = (off + bytes + 255) & ~(size_t)255;
    return p;
  };
  __hip_bfloat16* xlb  = (__hip_bfloat16*)alloc((size_t)N * HC * 2);  // 16 MB
  __hip_bfloat16* xrb  = (__hip_bfloat16*)alloc((size_t)N * HC * 2);  // 16 MB
  __hip_bfloat16* hb1  = (__hip_bfloat16*)alloc((size_t)N * HC * 2);  // 16 MB
  __hip_bfloat16* hb2  = (__hip_bfloat16*)alloc((size_t)N * HC * 2);  // 16 MB
  __hip_bfloat16* xbf  = (__hip_bfloat16*)alloc((size_t)N * FIN * 2);
  __hip_bfloat16* fpbf = (__hip_bfloat16*)alloc((size_t)G * FPIN * 2); // 4 MB
  __hip_bfloat16* wt1  = (__hip_bfloat16*)alloc((size_t)512 * FIN * 2);
  __hip_bfloat16* wt2  = (__hip_bfloat16*)alloc((size_t)512 * HC * 2);
  __hip_bfloat16* fwt  = (__hip_bfloat16*)alloc((size_t)256 * FPIN * 2); // 1 MB
  __hip_bfloat16* gwt  = (__hip_bfloat16*)alloc((size_t)64 * HC * 2);
  __hip_bfloat16* k1wt = (__hip_bfloat16*)alloc((size_t)192 * 384 * 2);
  __hip_bfloat16* xg   = (__hip_bfloat16*)alloc((size_t)G * HC * 2);
  __hip_bfloat16* zbuf = (__hip_bfloat16*)alloc((size_t)G * 384 * 2);
  float* z1      = (float*)alloc((size_t)G * 192 * 4);
  int*   deg     = (int*)alloc((size_t)N * 4);
  int*   csr_ptr = (int*)alloc((size_t)(N + 1) * 4);
  int*   cursor  = (int*)alloc((size_t)N * 4);
  int*   csr_src = (int*)alloc((size_t)E * 4);
  float* csr_ea  = (float*)alloc((size_t)E * 8 * 4);                  // 8 MB
  (void)ws_size;

  const int* srcp = edge_index;
  const int* dstp = edge_index + E;

  hipMemsetAsync(deg, 0, (size_t)N * 4, stream);

  // one prep kernel: conversions + weight transposes + degree count
  {
    long total = (long)N * FIN + (long)G * FPIN + 512 * 32 + 512 * 256 +
                 256 * 2048 + 64 * 256 + 192 * 384 + E;
    prep_kernel<<<(int)((total + 255) / 256), 256, 0, stream>>>(
        x, fp, c1_Wl, c1_Wr, c2_Wl, c2_Wr, fW, gW, k1W, dstp, deg,
        xbf, fpbf, wt1, wt2, fwt, gwt, k1wt, N, G, E);
  }
  scan_kernel<<<1, 1024, 0, stream>>>(deg, csr_ptr, cursor, N);
  fill_kernel<<<(E + 255) / 256, 256, 0, stream>>>(srcp, dstp, edge_attr, cursor,
                                                   csr_src, csr_ea, E);

  // fp branch (bf16 MFMA) -> zbuf[:,64:320]
  gemm_rb_kernel<<<dim3(G / 64, 4), 256, 0, stream>>>(fpbf, fwt, fb, f_gn, f_bt,
                                                      zbuf, G, FPIN, 384, 64, 1);
  // desc branch -> zbuf[:,320:384]
  dense_kernel<<<(G * 64 + 255) / 256, 256, 0, stream>>>(desc, dW, db, d_gn, d_bt,
                                                         zbuf, G, 64, DIN, 384, 320);

  // layer 1
  gemm_mfma_kernel<<<dim3(N / 128, 8), 256, 0, stream>>>(xbf, wt1, c1_bl, c1_br, xlb, xrb, N, FIN);
  gat_kernel<<<N / 2, 128, 0, stream>>>(xlb, xrb, csr_ea, csr_src, csr_ptr,
                                        c1_We, c1_att, c1_bias, hb1, N);
  // layer 2
  gemm_mfma_kernel<<<dim3(N / 128, 8), 256, 0, stream>>>(hb1, wt2, c2_bl, c2_br, xlb, xrb, N, HC);
  gat_kernel<<<N / 2, 128, 0, stream>>>(xlb, xrb, csr_ea, csr_src, csr_ptr,
                                        c2_We, c2_att, c2_bias, hb2, N);

  // pool (batch is sorted, N/G nodes per graph) -> bf16 xg
  pool_seg_kernel<<<G, 256, 0, stream>>>(hb2, xg, N / G);

  // g branch (bf16 MFMA) -> zbuf[:,0:64]
  gemm_rb_kernel<<<dim3(G / 64, 1), 256, 0, stream>>>(xg, gwt, gb, g_gn, g_bt,
                                                      zbuf, G, HC, 384, 0, 1);
  // k1 (bf16 MFMA) -> z1 fp32
  gemm_rb_kernel<<<dim3(G / 64, 3), 256, 0, stream>>>(zbuf, k1wt, k1b, k1_gn, k1_bt,
                                                      z1, G, 384, 192, 0, 0);
  head23_kernel<<<G / 16, 256, 0, stream>>>(z1, k2W, k2b, k2_gn, k2_bt, k3W, k3b, (float*)d_out);
}

// Round 9
// 519.173 us; speedup vs baseline: 2.9576x; 2.9576x over previous
//
#include <hip/hip_runtime.h>
#include <hip/hip_bf16.h>
#include <math.h>

#define NHEAD 4
#define HC 256

typedef short short8 __attribute__((ext_vector_type(8)));
typedef short short4v __attribute__((ext_vector_type(4)));
typedef float f32x4 __attribute__((ext_vector_type(4)));

__device__ inline f32x4 bf4_to_f32(short4v v)
{
  f32x4 r;
#pragma unroll
  for (int i = 0; i < 4; ++i)
    r[i] = __uint_as_float(((unsigned)(unsigned short)v[i]) << 16);
  return r;
}

// ------- one fused prep kernel: all fp32->bf16 conversions, all weight
// transposes/concats, and the degree count (grid-partitioned ranges) -------
__global__ void prep_kernel(
    const float* __restrict__ x, const float* __restrict__ fp,
    const float* __restrict__ c1Wl, const float* __restrict__ c1Wr,
    const float* __restrict__ c2Wl, const float* __restrict__ c2Wr,
    const float* __restrict__ fW, const float* __restrict__ gW,
    const float* __restrict__ k1W, const int* __restrict__ dst,
    int* __restrict__ deg,
    __hip_bfloat16* __restrict__ xbf, __hip_bfloat16* __restrict__ fpbf,
    __hip_bfloat16* __restrict__ wt1, __hip_bfloat16* __restrict__ wt2,
    __hip_bfloat16* __restrict__ fwt, __hip_bfloat16* __restrict__ gwt,
    __hip_bfloat16* __restrict__ k1wt, int N, int G, int E)
{
  const int n0 = N * 32, n1 = G * 2048, n2 = 512 * 32, n3 = 512 * 256;
  const int n4 = 256 * 2048, n5 = 64 * 256, n6 = 192 * 384;
  int idx = blockIdx.x * 256 + threadIdx.x;
  if (idx < n0) { xbf[idx] = __float2bfloat16(x[idx]); return; }
  idx -= n0;
  if (idx < n1) { fpbf[idx] = __float2bfloat16(fp[idx]); return; }
  idx -= n1;
  if (idx < n2) {
    int n = idx / 32, k = idx - n * 32;
    float v = (n < 256) ? c1Wl[k * 256 + n] : c1Wr[k * 256 + (n - 256)];
    wt1[idx] = __float2bfloat16(v); return;
  }
  idx -= n2;
  if (idx < n3) {
    int n = idx / 256, k = idx - n * 256;
    float v = (n < 256) ? c2Wl[k * 256 + n] : c2Wr[k * 256 + (n - 256)];
    wt2[idx] = __float2bfloat16(v); return;
  }
  idx -= n3;
  if (idx < n4) {
    int n = idx / 2048, k = idx - n * 2048;
    fwt[idx] = __float2bfloat16(fW[(long)k * 256 + n]); return;
  }
  idx -= n4;
  if (idx < n5) {
    int n = idx / 256, k = idx - n * 256;
    gwt[idx] = __float2bfloat16(gW[k * 64 + n]); return;
  }
  idx -= n5;
  if (idx < n6) {
    int n = idx / 384, k = idx - n * 384;
    k1wt[idx] = __float2bfloat16(k1W[k * 192 + n]); return;
  }
  idx -= n6;
  if (idx < E) atomicAdd(&deg[dst[idx]], 1);
}

// ------- bf16 MFMA GEMM: [xl|xr] = A[M][K] @ W[K][512] + bias -> bf16 tables -
__global__ __launch_bounds__(256) void gemm_mfma_kernel(
    const __hip_bfloat16* __restrict__ A, const __hip_bfloat16* __restrict__ BT,
    const float* __restrict__ bl, const float* __restrict__ br,
    __hip_bfloat16* __restrict__ XL, __hip_bfloat16* __restrict__ XR, int M, int K)
{
  __shared__ short As[128 * 40];
  __shared__ short Bs[64 * 40];
  int bm = blockIdx.x * 128, bn = blockIdx.y * 64;
  int t = threadIdx.x;
  int w = t >> 6, l = t & 63;
  int quad = l >> 4, l16 = l & 15;
  int col8 = (t & 3) * 8;

  f32x4 acc[2][4];
#pragma unroll
  for (int i = 0; i < 2; ++i)
#pragma unroll
    for (int j = 0; j < 4; ++j) acc[i][j] = (f32x4){0.f, 0.f, 0.f, 0.f};

  for (int k0 = 0; k0 < K; k0 += 32) {
#pragma unroll
    for (int p = 0; p < 2; ++p) {
      int row = (t >> 2) + p * 64;
      *(short8*)&As[row * 40 + col8] =
          *(const short8*)(const void*)&A[(long)(bm + row) * K + k0 + col8];
    }
    {
      int n = t >> 2;
      *(short8*)&Bs[n * 40 + col8] =
          *(const short8*)(const void*)&BT[(long)(bn + n) * K + k0 + col8];
    }
    __syncthreads();
    short8 af[2], bf[4];
#pragma unroll
    for (int mt = 0; mt < 2; ++mt)
      af[mt] = *(short8*)&As[(w * 32 + mt * 16 + l16) * 40 + quad * 8];
#pragma unroll
    for (int nt = 0; nt < 4; ++nt)
      bf[nt] = *(short8*)&Bs[(nt * 16 + l16) * 40 + quad * 8];
#pragma unroll
    for (int mt = 0; mt < 2; ++mt)
#pragma unroll
      for (int nt = 0; nt < 4; ++nt)
        acc[mt][nt] = __builtin_amdgcn_mfma_f32_16x16x32_bf16(af[mt], bf[nt], acc[mt][nt], 0, 0, 0);
    __syncthreads();
  }
#pragma unroll
  for (int mt = 0; mt < 2; ++mt)
#pragma unroll
    for (int nt = 0; nt < 4; ++nt) {
      int col = bn + nt * 16 + l16;
      float b = (col < 256) ? bl[col] : br[col - 256];
#pragma unroll
      for (int r = 0; r < 4; ++r) {
        int row = bm + w * 32 + mt * 16 + quad * 4 + r;
        float v = acc[mt][nt][r] + b;
        if (col < 256)
          XL[(long)row * 256 + col] = __float2bfloat16(v);
        else
          XR[(long)row * 256 + (col - 256)] = __float2bfloat16(v);
      }
    }
}

// ------- bf16 MFMA GEMM + relu + bn epilogue; out bf16 (obf=1) or fp32 -------
// A[M][K] bf16, BT[N][K] bf16 n-major. Tile 64x64, grid (M/64, N/64).
__global__ __launch_bounds__(256) void gemm_rb_kernel(
    const __hip_bfloat16* __restrict__ A, const __hip_bfloat16* __restrict__ BT,
    const float* __restrict__ bias, const float* __restrict__ gamma,
    const float* __restrict__ beta, void* __restrict__ out,
    int M, int K, int ldc, int coloff, int obf)
{
  __shared__ short As[64 * 40];
  __shared__ short Bs[64 * 40];
  int bm = blockIdx.x * 64, bn = blockIdx.y * 64;
  int t = threadIdx.x;
  int w = t >> 6, l = t & 63;
  int quad = l >> 4, l16 = l & 15;
  int lrow = t >> 2, col8 = (t & 3) * 8;

  f32x4 acc[4];
#pragma unroll
  for (int nt = 0; nt < 4; ++nt) acc[nt] = (f32x4){0.f, 0.f, 0.f, 0.f};

  for (int k0 = 0; k0 < K; k0 += 32) {
    *(short8*)&As[lrow * 40 + col8] =
        *(const short8*)(const void*)&A[(long)(bm + lrow) * K + k0 + col8];
    *(short8*)&Bs[lrow * 40 + col8] =
        *(const short8*)(const void*)&BT[(long)(bn + lrow) * K + k0 + col8];
    __syncthreads();
    short8 af = *(short8*)&As[(w * 16 + l16) * 40 + quad * 8];
#pragma unroll
    for (int nt = 0; nt < 4; ++nt) {
      short8 bf = *(short8*)&Bs[(nt * 16 + l16) * 40 + quad * 8];
      acc[nt] = __builtin_amdgcn_mfma_f32_16x16x32_bf16(af, bf, acc[nt], 0, 0, 0);
    }
    __syncthreads();
  }
  const float inv = rsqrtf(1.f + 1e-5f);
#pragma unroll
  for (int nt = 0; nt < 4; ++nt) {
    int col = bn + nt * 16 + l16;
    float b = bias[col], gm = gamma[col] * inv, bt = beta[col];
#pragma unroll
    for (int r = 0; r < 4; ++r) {
      int row = bm + w * 16 + quad * 4 + r;
      float v = fmaxf(acc[nt][r] + b, 0.f) * gm + bt;
      if (obf)
        ((__hip_bfloat16*)out)[(long)row * ldc + coloff + col] = __float2bfloat16(v);
      else
        ((float*)out)[(long)row * ldc + coloff + col] = v;
    }
  }
}

// -------- scalar dense layer (desc branch): out = bn(relu(A@W+b)) -> bf16 ---
__global__ __launch_bounds__(256) void dense_kernel(
    const float* __restrict__ A, const float* __restrict__ W,
    const float* __restrict__ bias, const float* __restrict__ gamma,
    const float* __restrict__ beta, __hip_bfloat16* __restrict__ out,
    int M, int Ncols, int K, int ldc, int coloff)
{
  int idx = blockIdx.x * 256 + threadIdx.x;
  if (idx >= M * Ncols) return;
  int row = idx / Ncols, col = idx - row * Ncols;
  const float* a = A + (long)row * K;
  float acc = 0.f;
#pragma unroll 4
  for (int k = 0; k < K; ++k) acc = fmaf(a[k], W[(long)k * Ncols + col], acc);
  const float inv = rsqrtf(1.f + 1e-5f);
  acc = fmaxf(acc + bias[col], 0.f) * (gamma[col] * inv) + beta[col];
  out[(long)row * ldc + coloff + col] = __float2bfloat16(acc);
}

// -------- fused k2+k3 head --------
__global__ __launch_bounds__(256) void head23_kernel(
    const float* __restrict__ z1, const float* __restrict__ k2W,
    const float* __restrict__ k2b, const float* __restrict__ k2_gn,
    const float* __restrict__ k2_bt, const float* __restrict__ k3W,
    const float* __restrict__ k3b, float* __restrict__ out)
{
  __shared__ float s1[16 * 192];
  __shared__ float s2[16 * 96];
  int b = blockIdx.x, t = threadIdx.x;
  for (int i = t; i < 16 * 192; i += 256) s1[i] = z1[(long)b * 16 * 192 + i];
  __syncthreads();
  const float inv = rsqrtf(1.f + 1e-5f);
#pragma unroll
  for (int j = 0; j < 6; ++j) {
    int idx = j * 256 + t;
    int row = idx / 96, col = idx - row * 96;
    float acc = 0.f;
#pragma unroll 4
    for (int k = 0; k < 192; ++k) acc = fmaf(s1[row * 192 + k], k2W[k * 96 + col], acc);
    acc = fmaxf(acc + k2b[col], 0.f);
    s2[idx] = acc * (k2_gn[col] * inv) + k2_bt[col];
  }
  __syncthreads();
  if (t < 192) {
    int row = t / 12, col = t - row * 12;
    float acc = 0.f;
#pragma unroll 4
    for (int k = 0; k < 96; ++k) acc = fmaf(s2[row * 96 + k], k3W[k * 12 + col], acc);
    out[(long)(b * 16 + row) * 12 + col] = acc + k3b[col];
  }
}

// ---------------- CSR build ----------------
__global__ __launch_bounds__(1024) void scan_kernel(
    const int* __restrict__ deg, int* __restrict__ ptr, int* __restrict__ cursor, int N)
{
  __shared__ int sums[1024];
  int t = threadIdx.x;
  int base = t * 32;
  int local[32];
  int s = 0;
#pragma unroll
  for (int i = 0; i < 32; ++i) {
    int v = (base + i < N) ? deg[base + i] : 0;
    local[i] = v; s += v;
  }
  sums[t] = s;
  __syncthreads();
  for (int off = 1; off < 1024; off <<= 1) {
    int v = (t >= off) ? sums[t - off] : 0;
    __syncthreads();
    sums[t] += v;
    __syncthreads();
  }
  int excl = sums[t] - s;
  for (int i = 0; i < 32; ++i) {
    if (base + i < N) { ptr[base + i] = excl; cursor[base + i] = excl; excl += local[i]; }
  }
  if (t == 1023) ptr[N] = sums[1023];
}

// scatter src id AND edge_attr into CSR order
__global__ void fill_kernel(const int* __restrict__ src, const int* __restrict__ dst,
                            const float* __restrict__ ea, int* __restrict__ cursor,
                            int* __restrict__ csr_src, float* __restrict__ csr_ea, int E)
{
  int e = blockIdx.x * blockDim.x + threadIdx.x;
  if (e < E) {
    int pos = atomicAdd(&cursor[dst[e]], 1);
    csr_src[pos] = src[e];
    f32x4 a0 = *(const f32x4*)(const void*)&ea[(long)e * 8];
    f32x4 a1 = *(const f32x4*)(const void*)&ea[(long)e * 8 + 4];
    *(f32x4*)&csr_ea[(long)pos * 8] = a0;
    *(f32x4*)&csr_ea[(long)pos * 8 + 4] = a1;
  }
}

// ---------------- GATv2 aggregation ----------------
// lane = head*16 + quad; lane owns 4 channels of one head; 2 nodes / 128-thr
// block. NO min-waves launch_bounds: forcing 8 waves/EU (R8) squeezed VGPR to
// 32 and spilled WeR/prefetch regs to scratch -> 2.4 GB traffic, 8x slower.
// Kernel needs ~64 VGPR; latency is adequately hidden at natural occupancy.
__global__ __launch_bounds__(128) void gat_kernel(
    const __hip_bfloat16* __restrict__ xlb, const __hip_bfloat16* __restrict__ xrb,
    const float* __restrict__ csr_ea, const int* __restrict__ csr_src,
    const int* __restrict__ csr_ptr,
    const float* __restrict__ We, const float* __restrict__ att,
    const float* __restrict__ bias, __hip_bfloat16* __restrict__ out, int N)
{
  int lane = threadIdx.x & 63;
  int node = blockIdx.x * 2 + (threadIdx.x >> 6);
  if (node >= N) return;
  int cbase = (lane >> 4) * 64 + (lane & 15) * 4;  // channel offset in [0,256)

  f32x4 attv = *(const f32x4*)(const void*)&att[cbase];
  f32x4 xriv = bf4_to_f32(*(const short4v*)(const void*)&xrb[(long)node * HC + cbase]);
  f32x4 biasv = *(const f32x4*)(const void*)&bias[cbase];
  f32x4 WeR[8];
#pragma unroll
  for (int d = 0; d < 8; ++d)
    WeR[d] = *(const f32x4*)(const void*)&We[d * HC + cbase];

  float rsum = 0.f;
  f32x4 acc = (f32x4){0.f, 0.f, 0.f, 0.f};
  f32x4 eas0 = (f32x4){0.f, 0.f, 0.f, 0.f};
  f32x4 eas1 = (f32x4){0.f, 0.f, 0.f, 0.f};

  int p0 = csr_ptr[node], p1 = csr_ptr[node + 1];

  auto edge_compute = [&](f32x4 xls, f32x4 ea0, f32x4 ea1) {
    f32x4 mv = xriv + xls;
#pragma unroll
    for (int d = 0; d < 4; ++d) mv += WeR[d] * ea0[d];
#pragma unroll
    for (int d = 0; d < 4; ++d) mv += WeR[d + 4] * ea1[d];
    float t = 0.f;
#pragma unroll
    for (int r = 0; r < 4; ++r) {
      float m = mv[r];
      m = (m > 0.f) ? m : 0.2f * m;
      t = fmaf(m, attv[r], t);
    }
    t += __shfl_xor(t, 1, 64);
    t += __shfl_xor(t, 2, 64);
    t += __shfl_xor(t, 4, 64);
    t += __shfl_xor(t, 8, 64);
    float p = __expf(t);
    rsum += p;
    acc += p * xls;
  };

  // 2-deep prefetch, named slots A/B (runtime-indexed arrays kill codegen)
  short4v xA = (short4v){0, 0, 0, 0}, xB = (short4v){0, 0, 0, 0};
  f32x4 a0A = (f32x4){0.f, 0.f, 0.f, 0.f}, a1A = a0A, a0B = a0A, a1B = a0A;
  if (p0 < p1) {
    int s = csr_src[p0];
    a0A = *(const f32x4*)(const void*)&csr_ea[(long)p0 * 8];
    a1A = *(const f32x4*)(const void*)&csr_ea[(long)p0 * 8 + 4];
    xA = *(const short4v*)(const void*)&xlb[(long)s * HC + cbase];
  }
  if (p0 + 1 < p1) {
    int s = csr_src[p0 + 1];
    a0B = *(const f32x4*)(const void*)&csr_ea[(long)(p0 + 1) * 8];
    a1B = *(const f32x4*)(const void*)&csr_ea[(long)(p0 + 1) * 8 + 4];
    xB = *(const short4v*)(const void*)&xlb[(long)s * HC + cbase];
  }
  int k = p0;
  for (; k + 2 <= p1; k += 2) {
    f32x4 e0 = a0A, e1 = a1A;
    short4v xc = xA;
    if (k + 2 < p1) {
      int s = csr_src[k + 2];
      a0A = *(const f32x4*)(const void*)&csr_ea[(long)(k + 2) * 8];
      a1A = *(const f32x4*)(const void*)&csr_ea[(long)(k + 2) * 8 + 4];
      xA = *(const short4v*)(const void*)&xlb[(long)s * HC + cbase];
    }
    eas0 += e0; eas1 += e1;
    edge_compute(bf4_to_f32(xc), e0, e1);

    e0 = a0B; e1 = a1B; xc = xB;
    if (k + 3 < p1) {
      int s = csr_src[k + 3];
      a0B = *(const f32x4*)(const void*)&csr_ea[(long)(k + 3) * 8];
      a1B = *(const f32x4*)(const void*)&csr_ea[(long)(k + 3) * 8 + 4];
      xB = *(const short4v*)(const void*)&xlb[(long)s * HC + cbase];
    }
    eas0 += e0; eas1 += e1;
    edge_compute(bf4_to_f32(xc), e0, e1);
  }
  if (k < p1) {           // odd tail lives in slot A
    eas0 += a0A; eas1 += a1A;
    edge_compute(bf4_to_f32(xA), a0A, a1A);
  }
  // self loop with mean edge_attr
  int cnt = p1 - p0;
  f32x4 xls_self = bf4_to_f32(*(const short4v*)(const void*)&xlb[(long)node * HC + cbase]);
  float invd = 1.f / (float)(cnt > 1 ? cnt : 1);
  edge_compute(xls_self, eas0 * invd, eas1 * invd);

  float invs = 1.f / rsum;
  short4v pk;
#pragma unroll
  for (int r = 0; r < 4; ++r) {
    float v = fmaxf(acc[r] * invs + biasv[r], 0.f);
    __hip_bfloat16 hv = __float2bfloat16(v);
    pk[r] = *(short*)&hv;
  }
  *(short4v*)&out[(long)node * HC + cbase] = pk;
}

// ---------------- segmented global max pool (bf16 in, bf16 out) ------------
__global__ __launch_bounds__(256) void pool_seg_kernel(
    const __hip_bfloat16* __restrict__ h, __hip_bfloat16* __restrict__ xg, int npg)
{
  int g = blockIdx.x, c = threadIdx.x;
  const __hip_bfloat16* base = h + (long)g * npg * HC + c;
  float m = -INFINITY;
#pragma unroll 4
  for (int i = 0; i < npg; ++i) {
    unsigned short u = *(const unsigned short*)&base[(long)i * HC];
    m = fmaxf(m, __uint_as_float(((unsigned)u) << 16));
  }
  xg[(long)g * HC + c] = __float2bfloat16(m);   // exact: max of bf16 values
}

extern "C" void kernel_launch(void* const* d_in, const int* in_sizes, int n_in,
                              void* d_out, int out_size, void* d_ws, size_t ws_size,
                              hipStream_t stream)
{
  const float* x          = (const float*)d_in[0];
  const int*   edge_index = (const int*)d_in[1];
  const float* edge_attr  = (const float*)d_in[2];
  const float* fp         = (const float*)d_in[4];
  const float* desc       = (const float*)d_in[5];
  const float *c1_Wl = (const float*)d_in[6],  *c1_bl = (const float*)d_in[7],
              *c1_Wr = (const float*)d_in[8],  *c1_br = (const float*)d_in[9],
              *c1_We = (const float*)d_in[10], *c1_att = (const float*)d_in[11],
              *c1_bias = (const float*)d_in[12];
  const float *c2_Wl = (const float*)d_in[13], *c2_bl = (const float*)d_in[14],
              *c2_Wr = (const float*)d_in[15], *c2_br = (const float*)d_in[16],
              *c2_We = (const float*)d_in[17], *c2_att = (const float*)d_in[18],
              *c2_bias = (const float*)d_in[19];
  const float *gW = (const float*)d_in[20], *gb = (const float*)d_in[21],
              *g_gn = (const float*)d_in[22], *g_bt = (const float*)d_in[23];
  const float *fW = (const float*)d_in[24], *fb = (const float*)d_in[25],
              *f_gn = (const float*)d_in[26], *f_bt = (const float*)d_in[27];
  const float *dW = (const float*)d_in[28], *db = (const float*)d_in[29],
              *d_gn = (const float*)d_in[30], *d_bt = (const float*)d_in[31];
  const float *k1W = (const float*)d_in[32], *k1b = (const float*)d_in[33],
              *k1_gn = (const float*)d_in[34], *k1_bt = (const float*)d_in[35];
  const float *k2W = (const float*)d_in[36], *k2b = (const float*)d_in[37],
              *k2_gn = (const float*)d_in[38], *k2_bt = (const float*)d_in[39];
  const float *k3W = (const float*)d_in[40], *k3b = (const float*)d_in[41];

  const int N = in_sizes[0] / 32;       // 32768
  const int E = in_sizes[1] / 2;        // 262144
  const int G = in_sizes[4] / 2048;     // 1024
  const int FIN = 32, FPIN = 2048;
  const int DIN = in_sizes[5] / G;      // 200

  char* ws = (char*)d_ws;
  size_t off = 0;
  auto alloc = [&](size_t bytes) {
    void* p = ws + off;
    off = (off + bytes + 255) & ~(size_t)255;
    return p;
  };
  __hip_bfloat16* xlb  = (__hip_bfloat16*)alloc((size_t)N * HC * 2);  // 16 MB
  __hip_bfloat16* xrb  = (__hip_bfloat16*)alloc((size_t)N * HC * 2);  // 16 MB
  __hip_bfloat16* hb1  = (__hip_bfloat16*)alloc((size_t)N * HC * 2);  // 16 MB
  __hip_bfloat16* hb2  = (__hip_bfloat16*)alloc((size_t)N * HC * 2);  // 16 MB
  __hip_bfloat16* xbf  = (__hip_bfloat16*)alloc((size_t)N * FIN * 2);
  __hip_bfloat16* fpbf = (__hip_bfloat16*)alloc((size_t)G * FPIN * 2); // 4 MB
  __hip_bfloat16* wt1  = (__hip_bfloat16*)alloc((size_t)512 * FIN * 2);
  __hip_bfloat16* wt2  = (__hip_bfloat16*)alloc((size_t)512 * HC * 2);
  __hip_bfloat16* fwt  = (__hip_bfloat16*)alloc((size_t)256 * FPIN * 2); // 1 MB
  __hip_bfloat16* gwt  = (__hip_bfloat16*)alloc((size_t)64 * HC * 2);
  __hip_bfloat16* k1wt = (__hip_bfloat16*)alloc((size_t)192 * 384 * 2);
  __hip_bfloat16* xg   = (__hip_bfloat16*)alloc((size_t)G * HC * 2);
  __hip_bfloat16* zbuf = (__hip_bfloat16*)alloc((size_t)G * 384 * 2);
  float* z1      = (float*)alloc((size_t)G * 192 * 4);
  int*   deg     = (int*)alloc((size_t)N * 4);
  int*   csr_ptr = (int*)alloc((size_t)(N + 1) * 4);
  int*   cursor  = (int*)alloc((size_t)N * 4);
  int*   csr_src = (int*)alloc((size_t)E * 4);
  float* csr_ea  = (float*)alloc((size_t)E * 8 * 4);                  // 8 MB
  (void)ws_size;

  const int* srcp = edge_index;
  const int* dstp = edge_index + E;

  hipMemsetAsync(deg, 0, (size_t)N * 4, stream);

  // one prep kernel: conversions + weight transposes + degree count
  {
    long total = (long)N * FIN + (long)G * FPIN + 512 * 32 + 512 * 256 +
                 256 * 2048 + 64 * 256 + 192 * 384 + E;
    prep_kernel<<<(int)((total + 255) / 256), 256, 0, stream>>>(
        x, fp, c1_Wl, c1_Wr, c2_Wl, c2_Wr, fW, gW, k1W, dstp, deg,
        xbf, fpbf, wt1, wt2, fwt, gwt, k1wt, N, G, E);
  }
  scan_kernel<<<1, 1024, 0, stream>>>(deg, csr_ptr, cursor, N);
  fill_kernel<<<(E + 255) / 256, 256, 0, stream>>>(srcp, dstp, edge_attr, cursor,
                                                   csr_src, csr_ea, E);

  // fp branch (bf16 MFMA) -> zbuf[:,64:320]
  gemm_rb_kernel<<<dim3(G / 64, 4), 256, 0, stream>>>(fpbf, fwt, fb, f_gn, f_bt,
                                                      zbuf, G, FPIN, 384, 64, 1);
  // desc branch -> zbuf[:,320:384]
  dense_kernel<<<(G * 64 + 255) / 256, 256, 0, stream>>>(desc, dW, db, d_gn, d_bt,
                                                         zbuf, G, 64, DIN, 384, 320);

  // layer 1
  gemm_mfma_kernel<<<dim3(N / 128, 8), 256, 0, stream>>>(xbf, wt1, c1_bl, c1_br, xlb, xrb, N, FIN);
  gat_kernel<<<N / 2, 128, 0, stream>>>(xlb, xrb, csr_ea, csr_src, csr_ptr,
                                        c1_We, c1_att, c1_bias, hb1, N);
  // layer 2
  gemm_mfma_kernel<<<dim3(N / 128, 8), 256, 0, stream>>>(hb1, wt2, c2_bl, c2_br, xlb, xrb, N, HC);
  gat_kernel<<<N / 2, 128, 0, stream>>>(xlb, xrb, csr_ea, csr_src, csr_ptr,
                                        c2_We, c2_att, c2_bias, hb2, N);

  // pool (batch is sorted, N/G nodes per graph) -> bf16 xg
  pool_seg_kernel<<<G, 256, 0, stream>>>(hb2, xg, N / G);

  // g branch (bf16 MFMA) -> zbuf[:,0:64]
  gemm_rb_kernel<<<dim3(G / 64, 1), 256, 0, stream>>>(xg, gwt, gb, g_gn, g_bt,
                                                      zbuf, G, HC, 384, 0, 1);
  // k1 (bf16 MFMA) -> z1 fp32
  gemm_rb_kernel<<<dim3(G / 64, 3), 256, 0, stream>>>(zbuf, k1wt, k1b, k1_gn, k1_bt,
                                                      z1, G, 384, 192, 0, 0);
  head23_kernel<<<G / 16, 256, 0, stream>>>(z1, k2W, k2b, k2_gn, k2_bt, k3W, k3b, (float*)d_out);
}